// Round 4
// baseline (593.419 us; speedup 1.0000x reference)
//
#include <hip/hip_runtime.h>

// MD-GRU (4-direction 2D GRU), block-resident wavefront scan, v4.
// 512 blocks x 512 threads (8 waves): 1 dir x 1 batch elem per block, 2 blocks/CU.
// All-bf16 h state in LDS (~21 KB/block) -> 16 waves/CU for cross-block latency
// hiding. 8 waves split N=384 eight ways; U^T persistent in registers.
// Workspace: [0,786432) U^T bf16 [a][n(384)][kk(256)]; then finals f32 [a][b][hh].

#define B_ 128
#define N_ 32
#define H_ 128
#define TH 384
#define KK 256

typedef short bf16x8 __attribute__((ext_vector_type(8)));
typedef float f32x4 __attribute__((ext_vector_type(4)));

__device__ inline ushort f2bf(float f) {
    unsigned u = __float_as_uint(f);
    return (ushort)((u + 0x7FFFu + ((u >> 16) & 1u)) >> 16);  // RNE
}
__device__ inline float bf2f(ushort u) {
    return __uint_as_float(((unsigned)u) << 16);
}
__device__ inline float fsig(float x) { return 1.0f / (1.0f + __expf(-x)); }
__device__ inline float ftanh2(float x) {  // tanh(x) = 2*sigmoid(2x) - 1
    float e = __expf(-2.0f * x);
    return __builtin_fmaf(2.0f, 1.0f / (1.0f + e), -1.0f);
}

// ---- U1,U2 (f32, [a][k][n]) -> U^T bf16 [a][n][kk], kk = mat*128 + k ----
__global__ void conv_u(const float* __restrict__ U1, const float* __restrict__ U2,
                       ushort* __restrict__ ubf) {
    __shared__ float t[32][33];
    int bx = blockIdx.x;
    int amat = bx / 48, tile = bx % 48;
    int kt = tile / 12, ntl = tile % 12;
    int a = amat >> 1, mat = amat & 1;
    int kk0 = kt * 32, n0 = ntl * 32;
    int tx = threadIdx.x, ty = threadIdx.y;
    const float* U = mat ? U2 : U1;
#pragma unroll
    for (int r = 0; r < 4; r++)
        t[ty + r * 8][tx] = U[(a * H_ + kk0 + ty + r * 8) * TH + n0 + tx];
    __syncthreads();
#pragma unroll
    for (int r = 0; r < 4; r++) {
        int n = n0 + ty + r * 8;
        int kkl = kk0 + tx;
        ubf[(a * TH + n) * KK + mat * H_ + kkl] = f2bf(t[tx][ty + r * 8]);
    }
}

// ---- persistent block-resident scan: 512 blocks x 512 threads (8 waves) ----
__global__ __launch_bounds__(512, 4) void scan_all(
    const float* __restrict__ x, const float* __restrict__ Wx,
    const float* __restrict__ bvec, const ushort* __restrict__ ubf,
    float* __restrict__ finals) {

    // bf16 h double buffer: [buf][slot(33)][hh(128)], XOR-swizzled within a row.
    // slot 0 = permanent zeros (boundary); cell i of a diagonal lives at slot i+1.
    __shared__ __align__(16) ushort hbf[2][33 * 128];
    __shared__ float xl[1024];  // pre-flipped x image for this (a, b)

    int bx = blockIdx.x;
    int a = bx >> 7, b = bx & 127;
    int tid = threadIdx.x;
    int lane = tid & 63, wn = tid >> 6;  // wn in [0,8): N-split
    int l16 = lane & 15, lg = lane >> 4;

    for (int idx = tid; idx < 33 * 128; idx += 512) ((unsigned*)hbf)[idx] = 0u;
    for (int idx = tid; idx < 1024; idx += 512) {
        int i = idx >> 5, j = idx & 31;
        int ri = (a & 1) ? (31 - i) : i;
        int cj = (a & 2) ? (31 - j) : j;
        xl[idx] = x[(b * N_ + ri) * N_ + cj];
    }

    // persistent U^T fragments: per wave 3 gates x 16 cols x K=256 -> 24 frags (96 VGPR)
    const ushort* ub = ubf + a * (TH * KK);
    bf16x8 Bf[3][8];
#pragma unroll
    for (int p = 0; p < 3; p++) {
        int n = p * H_ + wn * 16 + l16;
#pragma unroll
        for (int ks = 0; ks < 8; ks++)
            Bf[p][ks] = *(const bf16x8*)(ub + n * KK + ks * 32 + lg * 8);
    }

    int hh = wn * 16 + l16;
    float wxs[3], bs[3];
#pragma unroll
    for (int p = 0; p < 3; p++) {
        wxs[p] = Wx[a * TH + p * H_ + hh];
        bs[p] = bvec[a * TH + p * H_ + hh];
    }
    __syncthreads();

    for (int d = 0; d < 63; d++) {
        int ilo = (d > 31) ? (d - 31) : 0;
        int ihi = (d < 31) ? d : 31;
        int w = ihi - ilo + 1;
        int nmt = (w + 15) >> 4;  // 1 or 2
        int wr = d & 1, rd = wr ^ 1;

        const char* hb = (const char*)&hbf[rd][0];

        // per-mt A-load bases (lane row = cell, clamped to ihi for invalid lanes)
        int tb[2], txr[2], lb[2], lxr[2];
#pragma unroll
        for (int mt = 0; mt < 2; mt++) {
            int ci = mt * 16 + l16;
            int i = ilo + ci;
            int ic = (i < ihi) ? i : ihi;
            tb[mt] = ic * 256;               // top pred: slot ic
            txr[mt] = (ic & 7) << 4;
            lb[mt] = tb[mt] + 256;           // left pred: slot ic+1
            lxr[mt] = ((ic + 1) & 7) << 4;
        }

        f32x4 acc[2][3];
        bf16x8 Af[2][2];
#pragma unroll
        for (int mt = 0; mt < 2; mt++)
            if (mt < nmt)
                Af[0][mt] = *(const bf16x8*)(hb + tb[mt] + ((lg * 16) ^ txr[mt]));
#pragma unroll
        for (int ks = 0; ks < 8; ks++) {
            if (ks < 7) {
                int ks1 = ks + 1;
#pragma unroll
                for (int mt = 0; mt < 2; mt++)
                    if (mt < nmt) {
                        int base = (ks1 < 4) ? tb[mt] : lb[mt];
                        int sx = (ks1 < 4) ? txr[mt] : lxr[mt];
                        int off = base + ((((ks1 & 3) * 64) + lg * 16) ^ sx);
                        Af[ks1 & 1][mt] = *(const bf16x8*)(hb + off);
                    }
            }
#pragma unroll
            for (int p = 0; p < 3; p++)
#pragma unroll
                for (int mt = 0; mt < 2; mt++)
                    if (mt < nmt) {
                        f32x4 cin = (ks == 0) ? (f32x4){0.0f, 0.0f, 0.0f, 0.0f}
                                              : acc[mt][p];
                        acc[mt][p] = __builtin_amdgcn_mfma_f32_16x16x32_bf16(
                            Af[ks & 1][mt], Bf[p][ks], cin, 0, 0, 0);
                    }
        }

        // fused epilogue + write: gates, GRU mix (preds re-read as bf16), store bf16
        char* hbw = (char*)&hbf[wr][0];
#pragma unroll
        for (int mt = 0; mt < 2; mt++) {
            if (mt < nmt) {
#pragma unroll
                for (int r = 0; r < 4; r++) {
                    int ci = mt * 16 + lg * 4 + r;
                    int i = ilo + ci;
                    int ic = (i < ihi) ? i : ihi;
                    int j = d - ic;
                    float xb = xl[ic * 32 + j];
                    ushort hts = *(const ushort*)(hb + ic * 256 + ((hh * 2) ^ ((ic & 7) << 4)));
                    ushort hls = *(const ushort*)(hb + (ic + 1) * 256 + ((hh * 2) ^ (((ic + 1) & 7) << 4)));
                    float hs = bf2f(hts) + bf2f(hls);
                    float Gr = acc[mt][0][r];
                    float Gz = acc[mt][1][r];
                    float Gn = acc[mt][2][r];
                    float rg = fsig(__builtin_fmaf(xb, wxs[0], bs[0]) + Gr);
                    float zg = fsig(__builtin_fmaf(xb, wxs[1], bs[1]) + Gz);
                    float ng = ftanh2(__builtin_fmaf(rg, Gn, __builtin_fmaf(xb, wxs[2], bs[2])));
                    float hv = __builtin_fmaf(-zg, __builtin_fmaf(-0.5f, hs, ng), ng);
                    if (ci < w) {
                        int sl = i + 1;
                        *(ushort*)(hbw + sl * 256 + ((hh * 2) ^ ((sl & 7) << 4))) = f2bf(hv);
                        if (d == 62) finals[(a * B_ + b) * H_ + hh] = hv;
                    }
                }
            }
        }
        __syncthreads();
    }
}

// ---- final: concat 4 terminal h's -> logits -> log_softmax ----
__global__ void classify(const float* __restrict__ fin, const float* __restrict__ Wo,
                         const float* __restrict__ bo, float* __restrict__ out) {
    int b = blockIdx.x;
    int lane = threadIdx.x;  // 64
    float acc[10];
#pragma unroll
    for (int o = 0; o < 10; o++) acc[o] = 0.0f;
#pragma unroll
    for (int kkx = 0; kkx < 8; kkx++) {
        int k = kkx * 64 + lane;
        int a = k >> 7, hh = k & 127;
        float fh = fin[(a * B_ + b) * H_ + hh];
#pragma unroll
        for (int o = 0; o < 10; o++) acc[o] += fh * Wo[k * 10 + o];
    }
    float logits[10];
#pragma unroll
    for (int o = 0; o < 10; o++) {
        float v = acc[o];
#pragma unroll
        for (int off = 32; off; off >>= 1) v += __shfl_xor(v, off, 64);
        logits[o] = v + bo[o];
    }
    float m = logits[0];
#pragma unroll
    for (int o = 1; o < 10; o++) m = fmaxf(m, logits[o]);
    float s = 0.0f;
#pragma unroll
    for (int o = 0; o < 10; o++) s += __expf(logits[o] - m);
    float lse = m + __logf(s);
    if (lane == 0) {
#pragma unroll
        for (int o = 0; o < 10; o++) out[b * 10 + o] = logits[o] - lse;
    }
}

extern "C" void kernel_launch(void* const* d_in, const int* in_sizes, int n_in,
                              void* d_out, int out_size, void* d_ws, size_t ws_size,
                              hipStream_t stream) {
    const float* x = (const float*)d_in[0];
    const float* Wx = (const float*)d_in[1];
    const float* U1 = (const float*)d_in[2];
    const float* U2 = (const float*)d_in[3];
    const float* bv = (const float*)d_in[4];
    const float* Wo = (const float*)d_in[5];
    const float* bo = (const float*)d_in[6];
    float* out = (float*)d_out;

    char* ws = (char*)d_ws;
    ushort* ubf = (ushort*)ws;                // 786432 B
    float* finals = (float*)(ws + 786432);    // 4*128*128*4 = 256 KB

    hipLaunchKernelGGL(conv_u, dim3(384), dim3(32, 8), 0, stream, U1, U2, ubf);
    hipLaunchKernelGGL(scan_all, dim3(512), dim3(512), 0, stream, x, Wx, bv, ubf, finals);
    hipLaunchKernelGGL(classify, dim3(128), dim3(64), 0, stream, finals, Wo, bo, out);
}

// Round 5
// 327.907 us; speedup vs baseline: 1.8097x; 1.8097x over previous
//
#include <hip/hip_runtime.h>

// MD-GRU (4-direction 2D GRU), block-resident wavefront scan, v5.
// 256 blocks x 512 threads (8 waves): 1 dir x 2 batch elems per block.
// All-bf16 h in LDS (~41 KB), U^T persistent in registers (needs 256-VGPR
// budget -> __launch_bounds__(512,2); r4 showed 128-cap forces U re-fetch
// from global = 1.4 GB HBM). Conflict-free XOR swizzle: key=(slot*2+bl)&7
// into byte bits [6:4] -> every 8-lane b128 group covers all 32 banks.
// Workspace: [0,786432) U^T bf16 [a][n(384)][kk(256)]; then finals f32 [a][b][hh].

#define B_ 128
#define N_ 32
#define H_ 128
#define TH 384
#define KK 256

typedef short bf16x8 __attribute__((ext_vector_type(8)));
typedef float f32x4 __attribute__((ext_vector_type(4)));

__device__ inline ushort f2bf(float f) {
    unsigned u = __float_as_uint(f);
    return (ushort)((u + 0x7FFFu + ((u >> 16) & 1u)) >> 16);  // RNE
}
__device__ inline float bf2f(ushort u) {
    return __uint_as_float(((unsigned)u) << 16);
}
__device__ inline float fsig(float x) { return 1.0f / (1.0f + __expf(-x)); }
__device__ inline float ftanh2(float x) {  // tanh(x) = 2*sigmoid(2x) - 1
    float e = __expf(-2.0f * x);
    return __builtin_fmaf(2.0f, 1.0f / (1.0f + e), -1.0f);
}

// ---- U1,U2 (f32, [a][k][n]) -> U^T bf16 [a][n][kk], kk = mat*128 + k ----
__global__ void conv_u(const float* __restrict__ U1, const float* __restrict__ U2,
                       ushort* __restrict__ ubf) {
    __shared__ float t[32][33];
    int bx = blockIdx.x;
    int amat = bx / 48, tile = bx % 48;
    int kt = tile / 12, ntl = tile % 12;
    int a = amat >> 1, mat = amat & 1;
    int kk0 = kt * 32, n0 = ntl * 32;
    int tx = threadIdx.x, ty = threadIdx.y;
    const float* U = mat ? U2 : U1;
#pragma unroll
    for (int r = 0; r < 4; r++)
        t[ty + r * 8][tx] = U[(a * H_ + kk0 + ty + r * 8) * TH + n0 + tx];
    __syncthreads();
#pragma unroll
    for (int r = 0; r < 4; r++) {
        int n = n0 + ty + r * 8;
        int kkl = kk0 + tx;
        ubf[(a * TH + n) * KK + mat * H_ + kkl] = f2bf(t[tx][ty + r * 8]);
    }
}

// ---- persistent block-resident scan: 256 blocks x 512 threads (8 waves) ----
__global__ __launch_bounds__(512, 2) void scan_all(
    const float* __restrict__ x, const float* __restrict__ Wx,
    const float* __restrict__ bvec, const ushort* __restrict__ ubf,
    float* __restrict__ finals) {

    // bf16 h double buffer: [buf][slot(33)][bl(2)][hh(128)] = 512 B/slot.
    // slot 0 = permanent zeros; cell at row i lives at slot i+1.
    // byte within row: (hh*2) ^ (((slot*2+bl)&7)<<4)
    __shared__ __align__(16) ushort hbf[2][33 * 256];
    __shared__ float xl[2][1024];  // [bl][i*32+j] pre-flipped

    int bx = blockIdx.x;
    int a = bx >> 6, chunk = bx & 63;
    int tid = threadIdx.x;
    int lane = tid & 63, wn = tid >> 6;  // wn in [0,8): N-split (one 16-col tile/gate)
    int l16 = lane & 15, lg = lane >> 4;

    for (int idx = tid; idx < 2 * 33 * 128; idx += 512) ((unsigned*)hbf)[idx] = 0u;
    for (int idx = tid; idx < 2048; idx += 512) {
        int bl = idx >> 10, cell = idx & 1023;
        int i = cell >> 5, j = cell & 31;
        int ri = (a & 1) ? (31 - i) : i;
        int cj = (a & 2) ? (31 - j) : j;
        xl[bl][cell] = x[((chunk * 2 + bl) * N_ + ri) * N_ + cj];
    }

    // persistent U^T fragments: 3 gates x 16 cols x K=256 -> 24 frags (96 VGPR)
    const ushort* ub = ubf + a * (TH * KK);
    bf16x8 Bf[3][8];
#pragma unroll
    for (int p = 0; p < 3; p++) {
        int n = p * H_ + wn * 16 + l16;
#pragma unroll
        for (int ks = 0; ks < 8; ks++)
            Bf[p][ks] = *(const bf16x8*)(ub + n * KK + ks * 32 + lg * 8);
    }

    int hh = wn * 16 + l16;
    float wxs[3], bs[3];
#pragma unroll
    for (int p = 0; p < 3; p++) {
        wxs[p] = Wx[a * TH + p * H_ + hh];
        bs[p] = bvec[a * TH + p * H_ + hh];
    }
    __syncthreads();

    // A-row mapping: m = mt*16 + l16 -> cell index ci = m>>1, batch lane bl = m&1
    int ciA = l16 >> 1, blA = l16 & 1;

    for (int d = 0; d < 63; d++) {
        int ilo = (d > 31) ? (d - 31) : 0;
        int ihi = (d < 31) ? d : 31;
        int w = ihi - ilo + 1;
        int nmt = (w + 7) >> 3;  // tiles of 16 rows over 2w rows: 1..4
        int wr = d & 1, rd = wr ^ 1;

        const char* hb = (const char*)&hbf[rd][0];

        // per-mt A bases: top pred slot = ic, left pred slot = ic+1 (clamped)
        int tb[4], tk[4], lb[4], lk[4];
#pragma unroll
        for (int mt = 0; mt < 4; mt++) {
            int ci = mt * 8 + ciA;
            int i = ilo + ci;
            int ic = (i < ihi) ? i : ihi;
            tb[mt] = ic * 512 + blA * 256;
            tk[mt] = ((ic * 2 + blA) & 7) << 4;
            lb[mt] = tb[mt] + 512;
            lk[mt] = (((ic + 1) * 2 + blA) & 7) << 4;
        }

        f32x4 acc[4][3];
        bf16x8 Af[2][4];
#pragma unroll
        for (int mt = 0; mt < 4; mt++)
            if (mt < nmt)
                Af[0][mt] = *(const bf16x8*)(hb + tb[mt] + ((lg * 16) ^ tk[mt]));
#pragma unroll
        for (int ks = 0; ks < 8; ks++) {
            if (ks < 7) {
                int ks1 = ks + 1;
#pragma unroll
                for (int mt = 0; mt < 4; mt++)
                    if (mt < nmt) {
                        int base = (ks1 < 4) ? tb[mt] : lb[mt];
                        int key = (ks1 < 4) ? tk[mt] : lk[mt];
                        int off = base + ((((ks1 & 3) * 64) + lg * 16) ^ key);
                        Af[ks1 & 1][mt] = *(const bf16x8*)(hb + off);
                    }
            }
#pragma unroll
            for (int p = 0; p < 3; p++)
#pragma unroll
                for (int mt = 0; mt < 4; mt++)
                    if (mt < nmt) {
                        f32x4 cin = (ks == 0) ? (f32x4){0.0f, 0.0f, 0.0f, 0.0f}
                                              : acc[mt][p];
                        acc[mt][p] = __builtin_amdgcn_mfma_f32_16x16x32_bf16(
                            Af[ks & 1][mt], Bf[p][ks], cin, 0, 0, 0);
                    }
        }

        // fused epilogue + write: D rows m = mt*16 + lg*4 + r -> ci, bl
        char* hbw = (char*)&hbf[wr][0];
#pragma unroll
        for (int mt = 0; mt < 4; mt++) {
            if (mt < nmt) {
#pragma unroll
                for (int r = 0; r < 4; r++) {
                    int ci = mt * 8 + lg * 2 + (r >> 1);
                    int bl = r & 1;
                    int i = ilo + ci;
                    int ic = (i < ihi) ? i : ihi;
                    int j = d - ic;
                    float xb = xl[bl][ic * 32 + j];
                    ushort hts = *(const ushort*)(
                        hb + ic * 512 + bl * 256 + ((hh * 2) ^ (((ic * 2 + bl) & 7) << 4)));
                    ushort hls = *(const ushort*)(
                        hb + (ic + 1) * 512 + bl * 256 +
                        ((hh * 2) ^ ((((ic + 1) * 2 + bl) & 7) << 4)));
                    float hs = bf2f(hts) + bf2f(hls);
                    float Gr = acc[mt][0][r];
                    float Gz = acc[mt][1][r];
                    float Gn = acc[mt][2][r];
                    float rg = fsig(__builtin_fmaf(xb, wxs[0], bs[0]) + Gr);
                    float zg = fsig(__builtin_fmaf(xb, wxs[1], bs[1]) + Gz);
                    float ng = ftanh2(__builtin_fmaf(rg, Gn, __builtin_fmaf(xb, wxs[2], bs[2])));
                    float hv = __builtin_fmaf(-zg, __builtin_fmaf(-0.5f, hs, ng), ng);
                    if (ci < w) {
                        int sl = i + 1;
                        *(ushort*)(hbw + sl * 512 + bl * 256 +
                                   ((hh * 2) ^ (((sl * 2 + bl) & 7) << 4))) = f2bf(hv);
                        if (d == 62)
                            finals[(a * B_ + chunk * 2 + bl) * H_ + hh] = hv;
                    }
                }
            }
        }
        __syncthreads();
    }
}

// ---- final: concat 4 terminal h's -> logits -> log_softmax ----
__global__ void classify(const float* __restrict__ fin, const float* __restrict__ Wo,
                         const float* __restrict__ bo, float* __restrict__ out) {
    int b = blockIdx.x;
    int lane = threadIdx.x;  // 64
    float acc[10];
#pragma unroll
    for (int o = 0; o < 10; o++) acc[o] = 0.0f;
#pragma unroll
    for (int kkx = 0; kkx < 8; kkx++) {
        int k = kkx * 64 + lane;
        int a = k >> 7, hh = k & 127;
        float fh = fin[(a * B_ + b) * H_ + hh];
#pragma unroll
        for (int o = 0; o < 10; o++) acc[o] += fh * Wo[k * 10 + o];
    }
    float logits[10];
#pragma unroll
    for (int o = 0; o < 10; o++) {
        float v = acc[o];
#pragma unroll
        for (int off = 32; off; off >>= 1) v += __shfl_xor(v, off, 64);
        logits[o] = v + bo[o];
    }
    float m = logits[0];
#pragma unroll
    for (int o = 1; o < 10; o++) m = fmaxf(m, logits[o]);
    float s = 0.0f;
#pragma unroll
    for (int o = 0; o < 10; o++) s += __expf(logits[o] - m);
    float lse = m + __logf(s);
    if (lane == 0) {
#pragma unroll
        for (int o = 0; o < 10; o++) out[b * 10 + o] = logits[o] - lse;
    }
}

extern "C" void kernel_launch(void* const* d_in, const int* in_sizes, int n_in,
                              void* d_out, int out_size, void* d_ws, size_t ws_size,
                              hipStream_t stream) {
    const float* x = (const float*)d_in[0];
    const float* Wx = (const float*)d_in[1];
    const float* U1 = (const float*)d_in[2];
    const float* U2 = (const float*)d_in[3];
    const float* bv = (const float*)d_in[4];
    const float* Wo = (const float*)d_in[5];
    const float* bo = (const float*)d_in[6];
    float* out = (float*)d_out;

    char* ws = (char*)d_ws;
    ushort* ubf = (ushort*)ws;                // 786432 B
    float* finals = (float*)(ws + 786432);    // 4*128*128*4 = 256 KB

    hipLaunchKernelGGL(conv_u, dim3(384), dim3(32, 8), 0, stream, U1, U2, ubf);
    hipLaunchKernelGGL(scan_all, dim3(256), dim3(512), 0, stream, x, Wx, bv, ubf, finals);
    hipLaunchKernelGGL(classify, dim3(128), dim3(64), 0, stream, finals, Wo, bo, out);
}

// Round 6
// 257.493 us; speedup vs baseline: 2.3046x; 1.2735x over previous
//
#include <hip/hip_runtime.h>

// MD-GRU (4-direction 2D GRU), block-resident wavefront scan, v6.
// 256 blocks x 512 threads (8 waves): 1 dir x 2 batch elems per block.
// All-bf16 h in LDS (~41 KB); U^T persistent in registers — v5's compiler
// sank the 96-VGPR Bf array into per-step L2 reloads (VGPR_Count=116),
// so v6 pins it with keep-alive inline asm each iteration.
// Transcendentals via raw v_exp_f32/v_rcp_f32 (no IEEE divide sequences).
// Conflict-free XOR swizzle: key=(slot*2+bl)&7 into byte bits [6:4].
// Workspace: [0,786432) U^T bf16 [a][n(384)][kk(256)]; then finals f32 [a][b][hh].

#define B_ 128
#define N_ 32
#define H_ 128
#define TH 384
#define KK 256

typedef short bf16x8 __attribute__((ext_vector_type(8)));
typedef float f32x4 __attribute__((ext_vector_type(4)));

__device__ inline ushort f2bf(float f) {  // round-to-nearest (ties away), 2 ops
    return (ushort)((__float_as_uint(f) + 0x8000u) >> 16);
}
__device__ inline ushort f2bf_rne(float f) {
    unsigned u = __float_as_uint(f);
    return (ushort)((u + 0x7FFFu + ((u >> 16) & 1u)) >> 16);
}
__device__ inline float bf2f(ushort u) {
    return __uint_as_float(((unsigned)u) << 16);
}
#define L2E 1.44269504088896f
__device__ inline float fsig(float x) {  // sigmoid: rcp(1+exp2(-x*log2e))
    float e = __builtin_amdgcn_exp2f(x * -L2E);
    return __builtin_amdgcn_rcpf(1.0f + e);
}
__device__ inline float ftanh2(float x) {  // tanh(x) = 2*sigmoid(2x) - 1
    float e = __builtin_amdgcn_exp2f(x * (-2.0f * L2E));
    return __builtin_fmaf(2.0f, __builtin_amdgcn_rcpf(1.0f + e), -1.0f);
}

// ---- U1,U2 (f32, [a][k][n]) -> U^T bf16 [a][n][kk], kk = mat*128 + k ----
__global__ void conv_u(const float* __restrict__ U1, const float* __restrict__ U2,
                       ushort* __restrict__ ubf) {
    __shared__ float t[32][33];
    int bx = blockIdx.x;
    int amat = bx / 48, tile = bx % 48;
    int kt = tile / 12, ntl = tile % 12;
    int a = amat >> 1, mat = amat & 1;
    int kk0 = kt * 32, n0 = ntl * 32;
    int tx = threadIdx.x, ty = threadIdx.y;
    const float* U = mat ? U2 : U1;
#pragma unroll
    for (int r = 0; r < 4; r++)
        t[ty + r * 8][tx] = U[(a * H_ + kk0 + ty + r * 8) * TH + n0 + tx];
    __syncthreads();
#pragma unroll
    for (int r = 0; r < 4; r++) {
        int n = n0 + ty + r * 8;
        int kkl = kk0 + tx;
        ubf[(a * TH + n) * KK + mat * H_ + kkl] = f2bf_rne(t[tx][ty + r * 8]);
    }
}

// ---- persistent block-resident scan: 256 blocks x 512 threads (8 waves) ----
__global__ __launch_bounds__(512, 2) void scan_all(
    const float* __restrict__ x, const float* __restrict__ Wx,
    const float* __restrict__ bvec, const ushort* __restrict__ ubf,
    float* __restrict__ finals) {

    // bf16 h double buffer: [buf][slot(33)][bl(2)][hh(128)] = 512 B/slot.
    // slot 0 = permanent zeros; cell at row i lives at slot i+1.
    // byte within row: (hh*2) ^ (((slot*2+bl)&7)<<4)
    __shared__ __align__(16) ushort hbf[2][33 * 256];
    __shared__ float xl[2][1024];  // [bl][i*32+j] pre-flipped

    int bx = blockIdx.x;
    int a = bx >> 6, chunk = bx & 63;
    int tid = threadIdx.x;
    int lane = tid & 63, wn = tid >> 6;  // wn in [0,8): 16 hh-cols x 3 gates per wave
    int l16 = lane & 15, lg = lane >> 4;

    for (int idx = tid; idx < 2 * 33 * 128; idx += 512) ((unsigned*)hbf)[idx] = 0u;
    for (int idx = tid; idx < 2048; idx += 512) {
        int bl = idx >> 10, cell = idx & 1023;
        int i = cell >> 5, j = cell & 31;
        int ri = (a & 1) ? (31 - i) : i;
        int cj = (a & 2) ? (31 - j) : j;
        xl[bl][cell] = x[((chunk * 2 + bl) * N_ + ri) * N_ + cj];
    }

    // persistent U^T fragments: 3 gates x 16 cols x K=256 -> 24 frags (96 VGPR)
    const ushort* ub = ubf + a * (TH * KK);
    bf16x8 Bf[3][8];
#pragma unroll
    for (int p = 0; p < 3; p++) {
        int n = p * H_ + wn * 16 + l16;
#pragma unroll
        for (int ks = 0; ks < 8; ks++)
            Bf[p][ks] = *(const bf16x8*)(ub + n * KK + ks * 32 + lg * 8);
    }

    int hh = wn * 16 + l16;
    float wxs[3], bs[3];
#pragma unroll
    for (int p = 0; p < 3; p++) {
        wxs[p] = Wx[a * TH + p * H_ + hh];
        bs[p] = bvec[a * TH + p * H_ + hh];
    }
    __syncthreads();

    // A-row mapping: m = mt*16 + l16 -> cell ci = m>>1, batch lane bl = m&1
    int ciA = l16 >> 1, blA = l16 & 1;

    for (int d = 0; d < 63; d++) {
        // pin U^T fragments + gate scalars in registers across the loop
#pragma unroll
        for (int p = 0; p < 3; p++)
#pragma unroll
            for (int ks = 0; ks < 8; ks++)
                asm volatile("" : "+v"(Bf[p][ks]));
        asm volatile("" : "+v"(wxs[0]), "+v"(wxs[1]), "+v"(wxs[2]),
                          "+v"(bs[0]), "+v"(bs[1]), "+v"(bs[2]));

        int ilo = (d > 31) ? (d - 31) : 0;
        int ihi = (d < 31) ? d : 31;
        int w = ihi - ilo + 1;
        int nmt = (w + 7) >> 3;  // 16-row tiles over 2w rows: 1..4
        int wr = d & 1, rd = wr ^ 1;

        const char* hb = (const char*)&hbf[rd][0];

        // per-mt A bases: top pred slot = ic, left pred slot = ic+1 (clamped)
        int tb[4], tk[4], lb[4], lk[4];
#pragma unroll
        for (int mt = 0; mt < 4; mt++) {
            int ci = mt * 8 + ciA;
            int i = ilo + ci;
            int ic = (i < ihi) ? i : ihi;
            tb[mt] = ic * 512 + blA * 256;
            tk[mt] = ((ic * 2 + blA) & 7) << 4;
            lb[mt] = tb[mt] + 512;
            lk[mt] = (((ic + 1) * 2 + blA) & 7) << 4;
        }

        f32x4 acc[4][3];
        bf16x8 Af[2][4];
#pragma unroll
        for (int mt = 0; mt < 4; mt++)
            if (mt < nmt)
                Af[0][mt] = *(const bf16x8*)(hb + tb[mt] + ((lg * 16) ^ tk[mt]));
#pragma unroll
        for (int ks = 0; ks < 8; ks++) {
            if (ks < 7) {
                int ks1 = ks + 1;
#pragma unroll
                for (int mt = 0; mt < 4; mt++)
                    if (mt < nmt) {
                        int base = (ks1 < 4) ? tb[mt] : lb[mt];
                        int key = (ks1 < 4) ? tk[mt] : lk[mt];
                        int off = base + ((((ks1 & 3) * 64) + lg * 16) ^ key);
                        Af[ks1 & 1][mt] = *(const bf16x8*)(hb + off);
                    }
            }
#pragma unroll
            for (int p = 0; p < 3; p++)
#pragma unroll
                for (int mt = 0; mt < 4; mt++)
                    if (mt < nmt) {
                        f32x4 cin = (ks == 0) ? (f32x4){0.0f, 0.0f, 0.0f, 0.0f}
                                              : acc[mt][p];
                        acc[mt][p] = __builtin_amdgcn_mfma_f32_16x16x32_bf16(
                            Af[ks & 1][mt], Bf[p][ks], cin, 0, 0, 0);
                    }
        }

        // fused epilogue + write: D rows m = mt*16 + lg*4 + r -> ci, bl
        char* hbw = (char*)&hbf[wr][0];
#pragma unroll
        for (int mt = 0; mt < 4; mt++) {
            if (mt < nmt) {
#pragma unroll
                for (int r = 0; r < 4; r++) {
                    int ci = mt * 8 + lg * 2 + (r >> 1);
                    int bl = r & 1;
                    int i = ilo + ci;
                    int ic = (i < ihi) ? i : ihi;
                    int j = d - ic;
                    float xb = xl[bl][ic * 32 + j];
                    ushort hts = *(const ushort*)(
                        hb + ic * 512 + bl * 256 + ((hh * 2) ^ (((ic * 2 + bl) & 7) << 4)));
                    ushort hls = *(const ushort*)(
                        hb + (ic + 1) * 512 + bl * 256 +
                        ((hh * 2) ^ ((((ic + 1) * 2 + bl) & 7) << 4)));
                    float hs = bf2f(hts) + bf2f(hls);
                    float Gr = acc[mt][0][r];
                    float Gz = acc[mt][1][r];
                    float Gn = acc[mt][2][r];
                    float rg = fsig(__builtin_fmaf(xb, wxs[0], bs[0]) + Gr);
                    float zg = fsig(__builtin_fmaf(xb, wxs[1], bs[1]) + Gz);
                    float ng = ftanh2(__builtin_fmaf(rg, Gn, __builtin_fmaf(xb, wxs[2], bs[2])));
                    float hv = __builtin_fmaf(-zg, __builtin_fmaf(-0.5f, hs, ng), ng);
                    if (ci < w) {
                        int sl = i + 1;
                        *(ushort*)(hbw + sl * 512 + bl * 256 +
                                   ((hh * 2) ^ (((sl * 2 + bl) & 7) << 4))) = f2bf(hv);
                        if (d == 62)
                            finals[(a * B_ + chunk * 2 + bl) * H_ + hh] = hv;
                    }
                }
            }
        }
        __syncthreads();
    }
}

// ---- final: concat 4 terminal h's -> logits -> log_softmax ----
__global__ void classify(const float* __restrict__ fin, const float* __restrict__ Wo,
                         const float* __restrict__ bo, float* __restrict__ out) {
    int b = blockIdx.x;
    int lane = threadIdx.x;  // 64
    float acc[10];
#pragma unroll
    for (int o = 0; o < 10; o++) acc[o] = 0.0f;
#pragma unroll
    for (int kkx = 0; kkx < 8; kkx++) {
        int k = kkx * 64 + lane;
        int a = k >> 7, hh = k & 127;
        float fh = fin[(a * B_ + b) * H_ + hh];
#pragma unroll
        for (int o = 0; o < 10; o++) acc[o] += fh * Wo[k * 10 + o];
    }
    float logits[10];
#pragma unroll
    for (int o = 0; o < 10; o++) {
        float v = acc[o];
#pragma unroll
        for (int off = 32; off; off >>= 1) v += __shfl_xor(v, off, 64);
        logits[o] = v + bo[o];
    }
    float m = logits[0];
#pragma unroll
    for (int o = 1; o < 10; o++) m = fmaxf(m, logits[o]);
    float s = 0.0f;
#pragma unroll
    for (int o = 0; o < 10; o++) s += __expf(logits[o] - m);
    float lse = m + __logf(s);
    if (lane == 0) {
#pragma unroll
        for (int o = 0; o < 10; o++) out[b * 10 + o] = logits[o] - lse;
    }
}

extern "C" void kernel_launch(void* const* d_in, const int* in_sizes, int n_in,
                              void* d_out, int out_size, void* d_ws, size_t ws_size,
                              hipStream_t stream) {
    const float* x = (const float*)d_in[0];
    const float* Wx = (const float*)d_in[1];
    const float* U1 = (const float*)d_in[2];
    const float* U2 = (const float*)d_in[3];
    const float* bv = (const float*)d_in[4];
    const float* Wo = (const float*)d_in[5];
    const float* bo = (const float*)d_in[6];
    float* out = (float*)d_out;

    char* ws = (char*)d_ws;
    ushort* ubf = (ushort*)ws;                // 786432 B
    float* finals = (float*)(ws + 786432);    // 4*128*128*4 = 256 KB

    hipLaunchKernelGGL(conv_u, dim3(384), dim3(32, 8), 0, stream, U1, U2, ubf);
    hipLaunchKernelGGL(scan_all, dim3(256), dim3(512), 0, stream, x, Wx, bv, ubf, finals);
    hipLaunchKernelGGL(classify, dim3(128), dim3(64), 0, stream, finals, Wo, bo, out);
}

// Round 7
// 249.683 us; speedup vs baseline: 2.3767x; 1.0313x over previous
//
#include <hip/hip_runtime.h>

// MD-GRU (4-direction 2D GRU), block-resident wavefront scan, v7.
// 256 blocks x 512 threads (8 waves): 1 dir x 2 batch elems per block.
// U^T pinned in registers via definition-point volatile asm (v6's in-loop
// keep-alives were satisfied by reload-discard; a volatile asm RESULT cannot
// be rematerialized). h kept twice in LDS: hbf (A-swizzled, MFMA reads) and
// hmix (epilogue layout [slot][hh][bl], conflict-free b32 access).
// Workspace: [0,786432) U^T bf16 [a][n(384)][kk(256)]; then finals f32 [a][b][hh].

#define B_ 128
#define N_ 32
#define H_ 128
#define TH 384
#define KK 256
#define MSTR 260  // hmix slot stride in u16: [hh(128)][bl(2)] + 4 pad -> 4-bank group shift

typedef short bf16x8 __attribute__((ext_vector_type(8)));
typedef float f32x4 __attribute__((ext_vector_type(4)));

__device__ inline ushort f2bf(float f) {  // round-to-nearest (ties away)
    return (ushort)((__float_as_uint(f) + 0x8000u) >> 16);
}
__device__ inline ushort f2bf_rne(float f) {
    unsigned u = __float_as_uint(f);
    return (ushort)((u + 0x7FFFu + ((u >> 16) & 1u)) >> 16);
}
__device__ inline float bf2f_lo(unsigned u) {  // low u16 -> float
    return __uint_as_float(u << 16);
}
__device__ inline float bf2f_hi(unsigned u) {  // high u16 -> float
    return __uint_as_float(u & 0xFFFF0000u);
}
#define L2E 1.44269504088896f
__device__ inline float fsig(float x) {
    float e = __builtin_amdgcn_exp2f(x * -L2E);
    return __builtin_amdgcn_rcpf(1.0f + e);
}
__device__ inline float ftanh2(float x) {  // tanh(x) = 2*sigmoid(2x) - 1
    float e = __builtin_amdgcn_exp2f(x * (-2.0f * L2E));
    return __builtin_fmaf(2.0f, __builtin_amdgcn_rcpf(1.0f + e), -1.0f);
}

// ---- U1,U2 (f32, [a][k][n]) -> U^T bf16 [a][n][kk], kk = mat*128 + k ----
__global__ void conv_u(const float* __restrict__ U1, const float* __restrict__ U2,
                       ushort* __restrict__ ubf) {
    __shared__ float t[32][33];
    int bx = blockIdx.x;
    int amat = bx / 48, tile = bx % 48;
    int kt = tile / 12, ntl = tile % 12;
    int a = amat >> 1, mat = amat & 1;
    int kk0 = kt * 32, n0 = ntl * 32;
    int tx = threadIdx.x, ty = threadIdx.y;
    const float* U = mat ? U2 : U1;
#pragma unroll
    for (int r = 0; r < 4; r++)
        t[ty + r * 8][tx] = U[(a * H_ + kk0 + ty + r * 8) * TH + n0 + tx];
    __syncthreads();
#pragma unroll
    for (int r = 0; r < 4; r++) {
        int n = n0 + ty + r * 8;
        int kkl = kk0 + tx;
        ubf[(a * TH + n) * KK + mat * H_ + kkl] = f2bf_rne(t[tx][ty + r * 8]);
    }
}

// ---- persistent block-resident scan: 256 blocks x 512 threads (8 waves) ----
__global__ __launch_bounds__(512, 2) void scan_all(
    const float* __restrict__ x, const float* __restrict__ Wx,
    const float* __restrict__ bvec, const ushort* __restrict__ ubf,
    float* __restrict__ finals) {

    // hbf: A-operand buffer [buf][slot(33)][bl(2)][hh(128)], XOR key=(slot*2+bl)&7
    //      on byte bits [6:4] -> b128 A-reads conflict-free. Written only.
    // hmix: epilogue buffer [buf][slot(33)][hh(128)][bl(2)] (+4 pad u16/slot).
    // xl2: pre-flipped x, [cell][bl] float2.
    __shared__ __align__(16) ushort hbf[2][33 * 256];
    __shared__ __align__(8) ushort hmix[2][33 * MSTR];
    __shared__ float2 xl2[1024];

    int bx = blockIdx.x;
    int a = bx >> 6, chunk = bx & 63;
    int tid = threadIdx.x;
    int lane = tid & 63, wn = tid >> 6;  // wn in [0,8): 16 hh-cols x 3 gates per wave
    int l16 = lane & 15, lg = lane >> 4;

    for (int idx = tid; idx < 2 * 33 * 128; idx += 512) ((unsigned*)hbf)[idx] = 0u;
    for (int idx = tid; idx < 33 * MSTR; idx += 512) {
        hmix[0][idx] = 0;
        hmix[1][idx] = 0;
    }
    for (int idx = tid; idx < 2048; idx += 512) {
        int bl = idx & 1, cell = idx >> 1;
        int i = cell >> 5, j = cell & 31;
        int ri = (a & 1) ? (31 - i) : i;
        int cj = (a & 2) ? (31 - j) : j;
        (&xl2[cell].x)[bl] = x[((chunk * 2 + bl) * N_ + ri) * N_ + cj];
    }

    // persistent U^T fragments: 3 gates x 16 cols x K=256 -> 24 frags (96 VGPR).
    // Definition-point volatile asm: the asm result cannot be rematerialized,
    // forcing register residency across the d-loop.
    const ushort* ub = ubf + a * (TH * KK);
    bf16x8 Bf[3][8];
#pragma unroll
    for (int p = 0; p < 3; p++) {
        int n = p * H_ + wn * 16 + l16;
#pragma unroll
        for (int ks = 0; ks < 8; ks++) {
            Bf[p][ks] = *(const bf16x8*)(ub + n * KK + ks * 32 + lg * 8);
            asm volatile("" : "+v"(Bf[p][ks]));
        }
    }

    int hh = wn * 16 + l16;
    float wxs[3], bs[3];
#pragma unroll
    for (int p = 0; p < 3; p++) {
        wxs[p] = Wx[a * TH + p * H_ + hh];
        bs[p] = bvec[a * TH + p * H_ + hh];
        asm volatile("" : "+v"(wxs[p]), "+v"(bs[p]));
    }
    __syncthreads();

    // A-row mapping: m = mt*16 + l16 -> cell ci = m>>1, batch lane bl = m&1
    int ciA = l16 >> 1, blA = l16 & 1;

    for (int d = 0; d < 63; d++) {
        int ilo = (d > 31) ? (d - 31) : 0;
        int ihi = (d < 31) ? d : 31;
        int w = ihi - ilo + 1;
        int nmt = (w + 7) >> 3;  // 16-row tiles over 2w rows: 1..4
        int wr = d & 1, rd = wr ^ 1;

        const char* hb = (const char*)&hbf[rd][0];

        int tb[4], tk[4], lb[4], lk[4];
#pragma unroll
        for (int mt = 0; mt < 4; mt++) {
            int ci = mt * 8 + ciA;
            int i = ilo + ci;
            int ic = (i < ihi) ? i : ihi;
            tb[mt] = ic * 512 + blA * 256;
            tk[mt] = ((ic * 2 + blA) & 7) << 4;
            lb[mt] = tb[mt] + 512;
            lk[mt] = (((ic + 1) * 2 + blA) & 7) << 4;
        }

        f32x4 acc[4][3];
        bf16x8 Af[2][4];
#pragma unroll
        for (int mt = 0; mt < 4; mt++)
            if (mt < nmt)
                Af[0][mt] = *(const bf16x8*)(hb + tb[mt] + ((lg * 16) ^ tk[mt]));
#pragma unroll
        for (int ks = 0; ks < 8; ks++) {
            if (ks < 7) {
                int ks1 = ks + 1;
#pragma unroll
                for (int mt = 0; mt < 4; mt++)
                    if (mt < nmt) {
                        int base = (ks1 < 4) ? tb[mt] : lb[mt];
                        int key = (ks1 < 4) ? tk[mt] : lk[mt];
                        int off = base + ((((ks1 & 3) * 64) + lg * 16) ^ key);
                        Af[ks1 & 1][mt] = *(const bf16x8*)(hb + off);
                    }
            }
#pragma unroll
            for (int p = 0; p < 3; p++)
#pragma unroll
                for (int mt = 0; mt < 4; mt++)
                    if (mt < nmt) {
                        f32x4 cin = (ks == 0) ? (f32x4){0.0f, 0.0f, 0.0f, 0.0f}
                                              : acc[mt][p];
                        acc[mt][p] = __builtin_amdgcn_mfma_f32_16x16x32_bf16(
                            Af[ks & 1][mt], Bf[p][ks], cin, 0, 0, 0);
                    }
        }

        // fused epilogue: rows m = mt*16 + lg*4 + r -> (ci = mt*8+lg*2+(r>>1), bl = r&1)
        const ushort* hmr = &hmix[rd][0];
        ushort* hmw = &hmix[wr][0];
        char* hbw = (char*)&hbf[wr][0];
#pragma unroll
        for (int mt = 0; mt < 4; mt++) {
            if (mt < nmt) {
#pragma unroll
                for (int p2 = 0; p2 < 2; p2++) {
                    int ci = mt * 8 + lg * 2 + p2;
                    int i = ilo + ci;
                    int ic = (i < ihi) ? i : ihi;
                    int j = d - ic;
                    float2 xb2 = xl2[ic * 32 + j];
                    unsigned ht32 = *(const unsigned*)&hmr[ic * MSTR + hh * 2];
                    unsigned hl32 = *(const unsigned*)&hmr[(ic + 1) * MSTR + hh * 2];
                    float hv[2];
#pragma unroll
                    for (int bl = 0; bl < 2; bl++) {
                        int r = p2 * 2 + bl;
                        float xb = bl ? xb2.y : xb2.x;
                        float hs = bl ? (bf2f_hi(ht32) + bf2f_hi(hl32))
                                      : (bf2f_lo(ht32) + bf2f_lo(hl32));
                        float Gr = acc[mt][0][r];
                        float Gz = acc[mt][1][r];
                        float Gn = acc[mt][2][r];
                        float rg = fsig(__builtin_fmaf(xb, wxs[0], bs[0]) + Gr);
                        float zg = fsig(__builtin_fmaf(xb, wxs[1], bs[1]) + Gz);
                        float ng = ftanh2(
                            __builtin_fmaf(rg, Gn, __builtin_fmaf(xb, wxs[2], bs[2])));
                        hv[bl] = __builtin_fmaf(-zg, __builtin_fmaf(-0.5f, hs, ng), ng);
                    }
                    if (ci < w) {
                        int sl = i + 1;
                        unsigned pk = (unsigned)f2bf(hv[0]) | ((unsigned)f2bf(hv[1]) << 16);
                        *(unsigned*)&hmw[sl * MSTR + hh * 2] = pk;
                        *(ushort*)(hbw + sl * 512 +
                                   ((hh * 2) ^ (((sl * 2) & 7) << 4))) = (ushort)pk;
                        *(ushort*)(hbw + sl * 512 + 256 +
                                   ((hh * 2) ^ (((sl * 2 + 1) & 7) << 4))) =
                            (ushort)(pk >> 16);
                        if (d == 62) {
                            finals[(a * B_ + chunk * 2) * H_ + hh] = hv[0];
                            finals[(a * B_ + chunk * 2 + 1) * H_ + hh] = hv[1];
                        }
                    }
                }
            }
        }
        __syncthreads();
    }
}

// ---- final: concat 4 terminal h's -> logits -> log_softmax ----
__global__ void classify(const float* __restrict__ fin, const float* __restrict__ Wo,
                         const float* __restrict__ bo, float* __restrict__ out) {
    int b = blockIdx.x;
    int lane = threadIdx.x;  // 64
    float acc[10];
#pragma unroll
    for (int o = 0; o < 10; o++) acc[o] = 0.0f;
#pragma unroll
    for (int kkx = 0; kkx < 8; kkx++) {
        int k = kkx * 64 + lane;
        int a = k >> 7, hh = k & 127;
        float fh = fin[(a * B_ + b) * H_ + hh];
#pragma unroll
        for (int o = 0; o < 10; o++) acc[o] += fh * Wo[k * 10 + o];
    }
    float logits[10];
#pragma unroll
    for (int o = 0; o < 10; o++) {
        float v = acc[o];
#pragma unroll
        for (int off = 32; off; off >>= 1) v += __shfl_xor(v, off, 64);
        logits[o] = v + bo[o];
    }
    float m = logits[0];
#pragma unroll
    for (int o = 1; o < 10; o++) m = fmaxf(m, logits[o]);
    float s = 0.0f;
#pragma unroll
    for (int o = 0; o < 10; o++) s += __expf(logits[o] - m);
    float lse = m + __logf(s);
    if (lane == 0) {
#pragma unroll
        for (int o = 0; o < 10; o++) out[b * 10 + o] = logits[o] - lse;
    }
}

extern "C" void kernel_launch(void* const* d_in, const int* in_sizes, int n_in,
                              void* d_out, int out_size, void* d_ws, size_t ws_size,
                              hipStream_t stream) {
    const float* x = (const float*)d_in[0];
    const float* Wx = (const float*)d_in[1];
    const float* U1 = (const float*)d_in[2];
    const float* U2 = (const float*)d_in[3];
    const float* bv = (const float*)d_in[4];
    const float* Wo = (const float*)d_in[5];
    const float* bo = (const float*)d_in[6];
    float* out = (float*)d_out;

    char* ws = (char*)d_ws;
    ushort* ubf = (ushort*)ws;                // 786432 B
    float* finals = (float*)(ws + 786432);    // 4*128*128*4 = 256 KB

    hipLaunchKernelGGL(conv_u, dim3(384), dim3(32, 8), 0, stream, U1, U2, ubf);
    hipLaunchKernelGGL(scan_all, dim3(256), dim3(512), 0, stream, x, Wx, bv, ubf, finals);
    hipLaunchKernelGGL(classify, dim3(128), dim3(64), 0, stream, finals, Wo, bo, out);
}

// Round 8
// 154.287 us; speedup vs baseline: 3.8462x; 1.6183x over previous
//
#include <hip/hip_runtime.h>
#include <type_traits>

// MD-GRU (4-direction 2D GRU), block-resident wavefront scan, v8.
// Key change vs v7: FIXED-ROW indexing. All 32 grid rows are processed every
// step; row i's predecessors are always slots i (top) and i+1 (left), so every
// LDS address is loop-invariant (precomputed VGPR + compile-time immediate).
// x is pre-transposed to diagonal-major xd[d][i]. Validity = per-lane write
// mask (d >= i) + wave-uniform per-rowtile guards. This removes ~900 VALU
// addressing instructions per wave per step (v7 was VALU-issue-bound:
// 45% VALUBusy = 4.7K cyc/SIMD/step of mostly address math).
// hbf layout: [buf][ksplane(4)][slot(33)][bl(2)][32 bf16], XOR key=(slot&7)<<4
// on bits [6:4] of (bl*64+byte) -> A-reads/writes uniform 2-way (free).
// Workspace: [0,786432) U^T bf16 [a][n(384)][kk(256)]; then finals f32 [a][b][hh].

#define B_ 128
#define N_ 32
#define H_ 128
#define TH 384
#define KK 256

#define HBF_PLANE 4224   // 33 slots * 128 B
#define HBF_BUF   16896  // 4 planes
#define HMIX_SLOT 528    // 264 u16: [hh(128)][bl(2)] + 4 pad
#define HMIX_BUF  17424  // 33 * 528
#define XD_STEP   256    // 32 rows * float2

typedef short bf16x8 __attribute__((ext_vector_type(8)));
typedef float f32x4 __attribute__((ext_vector_type(4)));

__device__ inline ushort f2bf(float f) {  // round-to-nearest (ties away)
    return (ushort)((__float_as_uint(f) + 0x8000u) >> 16);
}
__device__ inline ushort f2bf_rne(float f) {
    unsigned u = __float_as_uint(f);
    return (ushort)((u + 0x7FFFu + ((u >> 16) & 1u)) >> 16);
}
__device__ inline float bf2f_lo(unsigned u) { return __uint_as_float(u << 16); }
__device__ inline float bf2f_hi(unsigned u) { return __uint_as_float(u & 0xFFFF0000u); }

#define NL2E -1.44269504088896f

// ---- U1,U2 (f32, [a][k][n]) -> U^T bf16 [a][n][kk], kk = mat*128 + k ----
__global__ void conv_u(const float* __restrict__ U1, const float* __restrict__ U2,
                       ushort* __restrict__ ubf) {
    __shared__ float t[32][33];
    int bx = blockIdx.x;
    int amat = bx / 48, tile = bx % 48;
    int kt = tile / 12, ntl = tile % 12;
    int a = amat >> 1, mat = amat & 1;
    int kk0 = kt * 32, n0 = ntl * 32;
    int tx = threadIdx.x, ty = threadIdx.y;
    const float* U = mat ? U2 : U1;
#pragma unroll
    for (int r = 0; r < 4; r++)
        t[ty + r * 8][tx] = U[(a * H_ + kk0 + ty + r * 8) * TH + n0 + tx];
    __syncthreads();
#pragma unroll
    for (int r = 0; r < 4; r++) {
        int n = n0 + ty + r * 8;
        int kkl = kk0 + tx;
        ubf[(a * TH + n) * KK + mat * H_ + kkl] = f2bf_rne(t[tx][ty + r * 8]);
    }
}

// ---- persistent block-resident scan: 256 blocks x 512 threads (8 waves) ----
__global__ __launch_bounds__(512, 2) void scan_all(
    const float* __restrict__ x, const float* __restrict__ Wx,
    const float* __restrict__ bvec, const ushort* __restrict__ ubf,
    float* __restrict__ finals) {

    __shared__ __align__(16) char hbf_c[2 * HBF_BUF];    // 33792 B
    __shared__ __align__(16) char hmix_c[2 * HMIX_BUF];  // 34848 B
    __shared__ __align__(16) char xd_c[63 * XD_STEP];    // 16128 B

    int bx = blockIdx.x;
    int a = bx >> 6, chunk = bx & 63;
    int tid = threadIdx.x;
    int lane = tid & 63, wn = tid >> 6;  // wn in [0,8): 16 hh-cols x 3 gates per wave
    int l16 = lane & 15, lg = lane >> 4;

    for (int idx = tid; idx < (2 * HBF_BUF) / 4; idx += 512) ((unsigned*)hbf_c)[idx] = 0u;
    for (int idx = tid; idx < (2 * HMIX_BUF) / 4; idx += 512) ((unsigned*)hmix_c)[idx] = 0u;
    for (int idx = tid; idx < (63 * XD_STEP) / 4; idx += 512) ((unsigned*)xd_c)[idx] = 0u;
    __syncthreads();

    // x -> diagonal-major LDS: xd[d][i] = {x_b0(i,d-i), x_b1(i,d-i)}
    const float* xg = x + (chunk * 2) * (N_ * N_);
    for (int cell = tid; cell < 1024; cell += 512) {
        int i = cell >> 5, j = cell & 31;
        int ri = (a & 1) ? (31 - i) : i;
        int cj = (a & 2) ? (31 - j) : j;
        float v0 = xg[ri * 32 + cj];
        float v1 = xg[1024 + ri * 32 + cj];
        *(float2*)(xd_c + (i + j) * XD_STEP + i * 8) = make_float2(v0, v1);
    }

    // persistent U^T fragments (96 VGPR/AGPR)
    const ushort* ub = ubf + a * (TH * KK);
    bf16x8 Bf[3][8];
#pragma unroll
    for (int p = 0; p < 3; p++) {
        int n = p * H_ + wn * 16 + l16;
#pragma unroll
        for (int ks = 0; ks < 8; ks++) {
            Bf[p][ks] = *(const bf16x8*)(ub + n * KK + ks * 32 + lg * 8);
            asm volatile("" : "+v"(Bf[p][ks]));
        }
    }

    int hh = wn * 16 + l16;
    float wxp[3], bsp[3];
    {
        float wr = Wx[a * TH + hh], br = bvec[a * TH + hh];
        float wz = Wx[a * TH + H_ + hh], bz = bvec[a * TH + H_ + hh];
        float wq = Wx[a * TH + 2 * H_ + hh], bq = bvec[a * TH + 2 * H_ + hh];
        wxp[0] = wr * NL2E; bsp[0] = br * NL2E;   // r-gate pre-scaled
        wxp[1] = wz * NL2E; bsp[1] = bz * NL2E;   // z-gate pre-scaled
        wxp[2] = wq;        bsp[2] = bq;          // n-gate unscaled
    }

    // loop-invariant LDS addresses
    int blA = l16 & 1;
    int aT[4], aL[4], hmR[4], wb[4][2][2];
#pragma unroll
    for (int mt = 0; mt < 4; mt++) {
        int st = mt * 8 + (l16 >> 1);                 // top slot for A-row
        aT[mt] = st * 128 + ((blA * 64 + lg * 16) ^ ((st & 7) << 4));
        int sl = st + 1;                              // left slot
        aL[mt] = sl * 128 + ((blA * 64 + lg * 16) ^ ((sl & 7) << 4));
        hmR[mt] = (mt * 8 + lg * 2) * HMIX_SLOT + hh * 4;
#pragma unroll
        for (int p2 = 0; p2 < 2; p2++) {
            int sw = mt * 8 + lg * 2 + p2 + 1;        // write slot
#pragma unroll
            for (int bl = 0; bl < 2; bl++)
                wb[mt][p2][bl] = (hh >> 5) * HBF_PLANE + sw * 128 +
                                 ((bl * 64 + (hh & 31) * 2) ^ ((sw & 7) << 4));
        }
    }

    const char* xdp = xd_c + lg * 16;

    __syncthreads();

    float fin0 = 0.0f, fin1 = 0.0f;

    auto step = [&](int d, auto WRC) {
        constexpr int WRB = decltype(WRC)::value;
        constexpr int RDB = WRB ^ 1;

        f32x4 acc[4][3];
#pragma unroll
        for (int mt = 0; mt < 4; mt++) {
            if (d >= mt * 8 && d < mt * 8 + 39) {  // wave-uniform
                bf16x8 af[4];
#pragma unroll
                for (int ks = 0; ks < 4; ks++)
                    af[ks] = *(const bf16x8*)(hbf_c + RDB * HBF_BUF + ks * HBF_PLANE + aT[mt]);
#pragma unroll
                for (int ks = 0; ks < 4; ks++)
#pragma unroll
                    for (int p = 0; p < 3; p++) {
                        f32x4 cin = (ks == 0) ? (f32x4){0.0f, 0.0f, 0.0f, 0.0f}
                                              : acc[mt][p];
                        acc[mt][p] = __builtin_amdgcn_mfma_f32_16x16x32_bf16(
                            af[ks], Bf[p][ks], cin, 0, 0, 0);
                    }
#pragma unroll
                for (int ks = 0; ks < 4; ks++)
                    af[ks] = *(const bf16x8*)(hbf_c + RDB * HBF_BUF + ks * HBF_PLANE + aL[mt]);
#pragma unroll
                for (int ks = 0; ks < 4; ks++)
#pragma unroll
                    for (int p = 0; p < 3; p++)
                        acc[mt][p] = __builtin_amdgcn_mfma_f32_16x16x32_bf16(
                            af[ks], Bf[p][ks + 4], acc[mt][p], 0, 0, 0);
            }
        }

#pragma unroll
        for (int mt = 0; mt < 4; mt++) {
            if (d >= mt * 8 && d < mt * 8 + 39) {
                unsigned hm0 = *(const unsigned*)(hmix_c + RDB * HMIX_BUF + hmR[mt]);
                unsigned hm1 = *(const unsigned*)(hmix_c + RDB * HMIX_BUF + hmR[mt] + HMIX_SLOT);
                unsigned hm2 = *(const unsigned*)(hmix_c + RDB * HMIX_BUF + hmR[mt] + 2 * HMIX_SLOT);
                f32x4 xv = *(const f32x4*)(xdp + WRB * 256 + mt * 64);
#pragma unroll
                for (int p2 = 0; p2 < 2; p2++) {
                    unsigned hmT = p2 ? hm1 : hm0;
                    unsigned hmL = p2 ? hm2 : hm1;
                    float hv[2];
#pragma unroll
                    for (int bl = 0; bl < 2; bl++) {
                        int r = p2 * 2 + bl;
                        float xb = xv[r];
                        float hs = bl ? (bf2f_hi(hmT) + bf2f_hi(hmL))
                                      : (bf2f_lo(hmT) + bf2f_lo(hmL));
                        float Gr = acc[mt][0][r];
                        float Gz = acc[mt][1][r];
                        float Gn = acc[mt][2][r];
                        float ar = __builtin_fmaf(Gr, NL2E, __builtin_fmaf(xb, wxp[0], bsp[0]));
                        float rg = __builtin_amdgcn_rcpf(1.0f + __builtin_amdgcn_exp2f(ar));
                        float az = __builtin_fmaf(Gz, NL2E, __builtin_fmaf(xb, wxp[1], bsp[1]));
                        float zg = __builtin_amdgcn_rcpf(1.0f + __builtin_amdgcn_exp2f(az));
                        float vn = __builtin_fmaf(rg, Gn, __builtin_fmaf(xb, wxp[2], bsp[2]));
                        float en = __builtin_amdgcn_exp2f(vn * (2.0f * NL2E));
                        float ng = __builtin_fmaf(2.0f, __builtin_amdgcn_rcpf(1.0f + en), -1.0f);
                        hv[bl] = __builtin_fmaf(-zg, __builtin_fmaf(-0.5f, hs, ng), ng);
                    }
                    int iRow = mt * 8 + lg * 2 + p2;
                    if (d >= iRow) {  // per-lane write mask
                        unsigned pk = (unsigned)f2bf(hv[0]) | ((unsigned)f2bf(hv[1]) << 16);
                        *(unsigned*)(hmix_c + WRB * HMIX_BUF + hmR[mt] + (p2 + 1) * HMIX_SLOT) = pk;
                        *(ushort*)(hbf_c + WRB * HBF_BUF + wb[mt][p2][0]) = (ushort)pk;
                        *(ushort*)(hbf_c + WRB * HBF_BUF + wb[mt][p2][1]) = (ushort)(pk >> 16);
                    }
                    if (mt == 3 && p2 == 1 && d == 62) {
                        fin0 = hv[0];
                        fin1 = hv[1];
                    }
                }
            }
        }
        __syncthreads();
    };

    for (int d = 0; d < 62; d += 2) {
        step(d, std::integral_constant<int, 0>{});
        step(d + 1, std::integral_constant<int, 1>{});
        xdp += 512;
    }
    step(62, std::integral_constant<int, 0>{});

    // terminal corner (row 31) lives on lanes lg==3 of mt=3/p2=1
    if (lg == 3) {
        finals[(a * B_ + chunk * 2) * H_ + hh] = fin0;
        finals[(a * B_ + chunk * 2 + 1) * H_ + hh] = fin1;
    }
}

// ---- final: concat 4 terminal h's -> logits -> log_softmax ----
__global__ void classify(const float* __restrict__ fin, const float* __restrict__ Wo,
                         const float* __restrict__ bo, float* __restrict__ out) {
    int b = blockIdx.x;
    int lane = threadIdx.x;  // 64
    float acc[10];
#pragma unroll
    for (int o = 0; o < 10; o++) acc[o] = 0.0f;
#pragma unroll
    for (int kkx = 0; kkx < 8; kkx++) {
        int k = kkx * 64 + lane;
        int a = k >> 7, hh = k & 127;
        float fh = fin[(a * B_ + b) * H_ + hh];
#pragma unroll
        for (int o = 0; o < 10; o++) acc[o] += fh * Wo[k * 10 + o];
    }
    float logits[10];
#pragma unroll
    for (int o = 0; o < 10; o++) {
        float v = acc[o];
#pragma unroll
        for (int off = 32; off; off >>= 1) v += __shfl_xor(v, off, 64);
        logits[o] = v + bo[o];
    }
    float m = logits[0];
#pragma unroll
    for (int o = 1; o < 10; o++) m = fmaxf(m, logits[o]);
    float s = 0.0f;
#pragma unroll
    for (int o = 0; o < 10; o++) s += __expf(logits[o] - m);
    float lse = m + __logf(s);
    if (lane == 0) {
#pragma unroll
        for (int o = 0; o < 10; o++) out[b * 10 + o] = logits[o] - lse;
    }
}

extern "C" void kernel_launch(void* const* d_in, const int* in_sizes, int n_in,
                              void* d_out, int out_size, void* d_ws, size_t ws_size,
                              hipStream_t stream) {
    const float* x = (const float*)d_in[0];
    const float* Wx = (const float*)d_in[1];
    const float* U1 = (const float*)d_in[2];
    const float* U2 = (const float*)d_in[3];
    const float* bv = (const float*)d_in[4];
    const float* Wo = (const float*)d_in[5];
    const float* bo = (const float*)d_in[6];
    float* out = (float*)d_out;

    char* ws = (char*)d_ws;
    ushort* ubf = (ushort*)ws;                // 786432 B
    float* finals = (float*)(ws + 786432);    // 4*128*128*4 = 256 KB

    hipLaunchKernelGGL(conv_u, dim3(384), dim3(32, 8), 0, stream, U1, U2, ubf);
    hipLaunchKernelGGL(scan_all, dim3(256), dim3(512), 0, stream, x, Wx, bv, ubf, finals);
    hipLaunchKernelGGL(classify, dim3(128), dim3(64), 0, stream, finals, Wo, bo, out);
}